// Round 16
// baseline (451.029 us; speedup 1.0000x reference)
//
#include <hip/hip_runtime.h>
#include <hip/hip_fp16.h>
#include <hip/hip_cooperative_groups.h>

namespace cg = cooperative_groups;

#define NN 131072   // nodes
#define EE 262144   // edges
#define GG 4096     // graphs

typedef _Float16 h2v __attribute__((ext_vector_type(2)));

#if __has_builtin(__builtin_amdgcn_fdot2)
#define FDOT2(a, b, c) __builtin_amdgcn_fdot2((a), (b), (c), false)
#else
#define FDOT2(a, b, c) ((float)(a)[0] * (float)(b)[0] + (float)(a)[1] * (float)(b)[1] + (c))
#endif

// ---------- fused front-end: zero+count+scan+fill+z in ONE cooperative kernel ----------
// 512 blocks x 256 threads; grid.sync() between phases.
__global__ __launch_bounds__(256) void k_front(const int* __restrict__ src,
                                               const int* __restrict__ dst,
                                               const float* __restrict__ x,
                                               const int* __restrict__ batch,
                                               int* __restrict__ indeg,
                                               int* __restrict__ bsum,
                                               int* __restrict__ boff,
                                               float* __restrict__ dinv,
                                               int* __restrict__ gstart,
                                               int* __restrict__ rowptr,
                                               int* __restrict__ cursor,
                                               int* __restrict__ ecol,
                                               float* __restrict__ ecoef,
                                               float* __restrict__ z) {
    cg::grid_group grid = cg::this_grid();
    int tid = threadIdx.x, b = blockIdx.x;
    __shared__ int sh[256];

    // P0: zero indeg
    indeg[b * 256 + tid] = 0;
    grid.sync();

    // P1: count in-degrees (2 edges/thread)
    {
        int e = b * 512 + tid;
        atomicAdd(&indeg[dst[e]], 1);
        atomicAdd(&indeg[dst[e + 256]], 1);
    }
    grid.sync();

    // P2: block totals + dinv + gstart (from sorted batch)
    {
        int gid = b * 256 + tid;
        int v = indeg[gid];
        dinv[gid] = rsqrtf((float)v + 1.0f);
        int b1v = batch[gid];
        int b0v = (gid == 0) ? -1 : batch[gid - 1];
        for (int g = b0v + 1; g <= b1v; ++g) gstart[g] = gid;
        if (gid == NN - 1)
            for (int g = b1v + 1; g <= GG; ++g) gstart[g] = NN;
        sh[tid] = v;
        __syncthreads();
#pragma unroll
        for (int off = 128; off > 0; off >>= 1) {
            if (tid < off) sh[tid] += sh[tid + off];
            __syncthreads();
        }
        if (tid == 0) bsum[b] = sh[0];
        __syncthreads();
    }
    grid.sync();

    // P3: block 0 scans the 512 block sums -> boff[513]
    if (b == 0) {
        int a0 = bsum[2 * tid], a1 = bsum[2 * tid + 1];
        int pair = a0 + a1;
        sh[tid] = pair;
        __syncthreads();
        for (int off = 1; off < 256; off <<= 1) {
            int v = (tid >= off) ? sh[tid - off] : 0;
            __syncthreads();
            sh[tid] += v;
            __syncthreads();
        }
        int incl = sh[tid];
        int excl = incl - pair;
        boff[2 * tid] = excl;
        boff[2 * tid + 1] = excl + a0;
        if (tid == 255) boff[512] = incl;
    }
    grid.sync();

    // P4: per-block local exclusive scan -> rowptr & cursor
    {
        int gid = b * 256 + tid;
        int v = indeg[gid];
        sh[tid] = v;
        __syncthreads();
        for (int off = 1; off < 256; off <<= 1) {
            int t2 = (tid >= off) ? sh[tid - off] : 0;
            __syncthreads();
            sh[tid] += t2;
            __syncthreads();
        }
        int excl = boff[b] + sh[tid] - v;
        rowptr[gid] = excl;
        cursor[gid] = excl;
        if (gid == NN - 1) rowptr[NN] = boff[512];
    }
    grid.sync();

    // P5: fill ecol/ecoef (2 edges/thread)
    {
#pragma unroll
        for (int q = 0; q < 2; ++q) {
            int e = b * 512 + tid + q * 256;
            int d = dst[e], s = src[e];
            int slot = atomicAdd(&cursor[d], 1);
            ecol[slot] = s;
            ecoef[slot] = dinv[d] * dinv[s];
        }
    }
    grid.sync();

    // P6: conv1 scalar z[i] = x_i*dinv_i^2 + sum_e ecoef*x[ecol]
    {
        int i = b * 256 + tid;
        float di = dinv[i];
        float s = x[i] * di * di;
        int e0 = rowptr[i], e1 = rowptr[i + 1];
        for (int e = e0; e < e1; ++e) s += ecoef[e] * x[ecol[e]];
        z[i] = s;
    }
}

// ---------- fused conv2: rh = fp16( relu( [Â relu(z⊗W1+b1)] @ W2 + b2 ) ) ----------
// MM in packed fp16 via v_dot2_f32_f16. LDS ~25KB -> 6 blocks/CU.  (R13 version)
__global__ __launch_bounds__(256) void k_gemm2u(const float* __restrict__ z,
                                                const float* __restrict__ dinv,
                                                const int* __restrict__ rowptr,
                                                const int* __restrict__ ecol,
                                                const float* __restrict__ ecoef,
                                                const float* __restrict__ W1,
                                                const float* __restrict__ b1,
                                                const float* __restrict__ W2,
                                                const float* __restrict__ b2,
                                                __half* __restrict__ rh) {
    __shared__ h2v At[64][33];    // [row][k-pair]
    __shared__ h2v Wt[32][128];   // [k-pair][col] — entire W2 in fp16 (16KB)
    __shared__ float w1s[64], b1s[64];

    int tid = threadIdx.x;
    int i0 = blockIdx.x * 64;

    if (tid < 64) { w1s[tid] = W1[tid]; b1s[tid] = b1[tid]; }
    {   // stage W2 as k-paired fp16
        int c4 = tid & 31, kp0 = tid >> 5;
#pragma unroll
        for (int p = 0; p < 4; ++p) {
            int kp = kp0 + p * 8;
            const float4 lo = *(const float4*)&W2[(size_t)(2 * kp) * 128 + c4 * 4];
            const float4 hi = *(const float4*)&W2[(size_t)(2 * kp + 1) * 128 + c4 * 4];
            h2v h0, h1, h2_, h3;
            h0[0] = (_Float16)lo.x; h0[1] = (_Float16)hi.x;
            h1[0] = (_Float16)lo.y; h1[1] = (_Float16)hi.y;
            h2_[0] = (_Float16)lo.z; h2_[1] = (_Float16)hi.z;
            h3[0] = (_Float16)lo.w; h3[1] = (_Float16)hi.w;
            Wt[kp][c4 * 4 + 0] = h0;
            Wt[kp][c4 * 4 + 1] = h1;
            Wt[kp][c4 * 4 + 2] = h2_;
            Wt[kp][c4 * 4 + 3] = h3;
        }
    }
    __syncthreads();

    {   // generate u rows: 4 threads per node, 16 k's each
        int n = tid >> 2;
        int kp0 = (tid & 3) * 8;
        int i = i0 + n;
        float zi = z[i], di = dinv[i];
        float d2 = di * di;
        float uacc[16];
#pragma unroll
        for (int j = 0; j < 16; ++j)
            uacc[j] = d2 * fmaxf(zi * w1s[kp0 * 2 + j] + b1s[kp0 * 2 + j], 0.f);
        int e0 = rowptr[i], e1 = rowptr[i + 1];
        for (int e = e0; e < e1; ++e) {
            float w = ecoef[e];
            float zs = z[ecol[e]];
#pragma unroll
            for (int j = 0; j < 16; ++j)
                uacc[j] += w * fmaxf(zs * w1s[kp0 * 2 + j] + b1s[kp0 * 2 + j], 0.f);
        }
#pragma unroll
        for (int j2 = 0; j2 < 8; ++j2) {
            h2v h;
            h[0] = (_Float16)uacc[2 * j2];
            h[1] = (_Float16)uacc[2 * j2 + 1];
            At[n][kp0 + j2] = h;
        }
    }
    __syncthreads();

    int colg = tid & 15;
    int rowg = tid >> 4;
    float acc[4][8];
#pragma unroll
    for (int rr = 0; rr < 4; ++rr)
#pragma unroll
        for (int c = 0; c < 8; ++c) acc[rr][c] = 0.0f;

#pragma unroll 4
    for (int kp = 0; kp < 32; ++kp) {
        h2v a2[4];
#pragma unroll
        for (int rr = 0; rr < 4; ++rr) a2[rr] = At[rowg * 4 + rr][kp];
        h2v wv[8];
        *(float4*)&wv[0] = *(const float4*)&Wt[kp][colg * 4];
        *(float4*)&wv[4] = *(const float4*)&Wt[kp][64 + colg * 4];
#pragma unroll
        for (int rr = 0; rr < 4; ++rr)
#pragma unroll
            for (int c = 0; c < 8; ++c)
                acc[rr][c] = FDOT2(a2[rr], wv[c], acc[rr][c]);
    }

#pragma unroll
    for (int rr = 0; rr < 4; ++rr) {
        int i = i0 + rowg * 4 + rr;
#pragma unroll
        for (int h = 0; h < 2; ++h) {
            int j = h * 64 + colg * 4;
            const float4 b = *(const float4*)&b2[j];
            __half2 p0 = __floats2half2_rn(fmaxf(acc[rr][h * 4 + 0] + b.x, 0.f),
                                           fmaxf(acc[rr][h * 4 + 1] + b.y, 0.f));
            __half2 p1 = __floats2half2_rn(fmaxf(acc[rr][h * 4 + 2] + b.z, 0.f),
                                           fmaxf(acc[rr][h * 4 + 3] + b.w, 0.f));
            union { __half2 h2[2]; float2 f; } u;
            u.h2[0] = p0; u.h2[1] = p1;
            *(float2*)&rh[(size_t)i * 128 + j] = u.f;
        }
    }
}

// fp16 row loader: 8 channels (16B) -> 8 floats
__device__ inline void ldr8(const __half* __restrict__ rh, size_t idx, float* o) {
    union { float4 f; __half2 h[4]; } u;
    u.f = *(const float4*)&rh[idx];
#pragma unroll
    for (int q = 0; q < 4; ++q) {
        float2 t = __half22float2(u.h[q]);
        o[q * 2] = t.x; o[q * 2 + 1] = t.y;
    }
}

// ---------- Y_g = mean_{i in g}(Â r)_i over fp16 r, 16 row-streams/block ----------
__global__ __launch_bounds__(256) void k_pool(const __half* __restrict__ rh,
                                              const float* __restrict__ dinv,
                                              const int* __restrict__ rowptr,
                                              const int* __restrict__ ecol,
                                              const float* __restrict__ ecoef,
                                              const int* __restrict__ gstart,
                                              float* __restrict__ Y,
                                              float* __restrict__ cntf) {
    int g = blockIdx.x, tid = threadIdx.x;
    int lo = gstart[g], hi = gstart[g + 1];
    int cnt = hi - lo;

    int lane = tid & 15, ty = tid >> 4;
    int c = lane * 8;
    float acc[8];
#pragma unroll
    for (int q = 0; q < 8; ++q) acc[q] = 0.f;
    float v0[8], v1[8], v2[8], v3[8];

    int i = lo + ty;
    for (; i + 16 < hi; i += 32) {
        float d0 = dinv[i], d1 = dinv[i + 16];
        ldr8(rh, (size_t)i * 128 + c, v0);
        ldr8(rh, (size_t)(i + 16) * 128 + c, v1);
        float w0 = d0 * d0, w1 = d1 * d1;
#pragma unroll
        for (int q = 0; q < 8; ++q) acc[q] += v0[q] * w0 + v1[q] * w1;
    }
    for (; i < hi; i += 16) {
        float di = dinv[i], d2 = di * di;
        ldr8(rh, (size_t)i * 128 + c, v0);
#pragma unroll
        for (int q = 0; q < 8; ++q) acc[q] += v0[q] * d2;
    }

    int e0 = rowptr[lo], e1 = rowptr[hi];
    int e = e0 + ty;
    for (; e + 48 < e1; e += 64) {
        int s0 = ecol[e], s1 = ecol[e + 16], s2 = ecol[e + 32], s3 = ecol[e + 48];
        float w0 = ecoef[e], w1 = ecoef[e + 16], w2 = ecoef[e + 32], w3 = ecoef[e + 48];
        ldr8(rh, (size_t)s0 * 128 + c, v0);
        ldr8(rh, (size_t)s1 * 128 + c, v1);
        ldr8(rh, (size_t)s2 * 128 + c, v2);
        ldr8(rh, (size_t)s3 * 128 + c, v3);
#pragma unroll
        for (int q = 0; q < 8; ++q)
            acc[q] += v0[q] * w0 + v1[q] * w1 + v2[q] * w2 + v3[q] * w3;
    }
    for (; e < e1; e += 16) {
        int s = ecol[e];
        float w = ecoef[e];
        ldr8(rh, (size_t)s * 128 + c, v0);
#pragma unroll
        for (int q = 0; q < 8; ++q) acc[q] += v0[q] * w;
    }

    __shared__ float red[16][128];
    *(float4*)&red[ty][c]     = make_float4(acc[0], acc[1], acc[2], acc[3]);
    *(float4*)&red[ty][c + 4] = make_float4(acc[4], acc[5], acc[6], acc[7]);
    __syncthreads();
    if (tid < 128) {
        float s = 0.0f;
#pragma unroll
        for (int t = 0; t < 16; ++t) s += red[t][tid];
        float inv = (cnt > 0) ? 1.0f / (float)cnt : 0.0f;
        Y[(size_t)g * 128 + tid] = s * inv;
    }
    if (tid == 0) cntf[g] = (float)cnt;
}

// ---------- generic register-tiled GEMM: C = [relu](A @ W + bias[*flag]) ----------
template <int K, int OUTW, bool RELU_OUT, bool GUARD>
__global__ __launch_bounds__(256) void k_gemm(const float* __restrict__ A,
                                              const float* __restrict__ W,
                                              const float* __restrict__ bias,
                                              const float* __restrict__ cntf,
                                              float* __restrict__ C) {
    __shared__ float At[64][68];
    __shared__ float Wt[64][128];

    int tid  = threadIdx.x;
    int colg = tid & 15;
    int rowg = tid >> 4;
    int i0 = blockIdx.x * 64;
    int j0 = blockIdx.y * 128;

    float acc[4][8];
#pragma unroll
    for (int r = 0; r < 4; ++r)
#pragma unroll
        for (int c = 0; c < 8; ++c) acc[r][c] = 0.0f;

    for (int k0 = 0; k0 < K; k0 += 64) {
        __syncthreads();
        {
            int k4 = tid & 15, r0 = tid >> 4;
#pragma unroll
            for (int p = 0; p < 4; ++p) {
                int r = r0 + p * 16;
                *(float4*)&At[r][k4 * 4] =
                    *(const float4*)&A[(size_t)(i0 + r) * K + k0 + k4 * 4];
            }
        }
        {
            int c4 = tid & 31, kk0 = tid >> 5;
#pragma unroll
            for (int p = 0; p < 8; ++p) {
                int kk = kk0 + p * 8;
                *(float4*)&Wt[kk][c4 * 4] =
                    *(const float4*)&W[(size_t)(k0 + kk) * OUTW + j0 + c4 * 4];
            }
        }
        __syncthreads();
#pragma unroll 4
        for (int kk = 0; kk < 64; ++kk) {
            float a[4];
#pragma unroll
            for (int r = 0; r < 4; ++r) a[r] = At[rowg * 4 + r][kk];
            const float4 w0 = *(const float4*)&Wt[kk][colg * 4];
            const float4 w1 = *(const float4*)&Wt[kk][64 + colg * 4];
            float w[8] = {w0.x, w0.y, w0.z, w0.w, w1.x, w1.y, w1.z, w1.w};
#pragma unroll
            for (int r = 0; r < 4; ++r)
#pragma unroll
                for (int c = 0; c < 8; ++c) acc[r][c] += a[r] * w[c];
        }
    }

#pragma unroll
    for (int r = 0; r < 4; ++r) {
        int i = i0 + rowg * 4 + r;
        float flag = 1.0f;
        if (GUARD) flag = (cntf[i] > 0.0f) ? 1.0f : 0.0f;
#pragma unroll
        for (int h = 0; h < 2; ++h) {
            int j = j0 + h * 64 + colg * 4;
            const float4 b = *(const float4*)&bias[j];
            float4 v;
            v.x = acc[r][h * 4 + 0] + b.x * flag;
            v.y = acc[r][h * 4 + 1] + b.y * flag;
            v.z = acc[r][h * 4 + 2] + b.z * flag;
            v.w = acc[r][h * 4 + 3] + b.w * flag;
            if (RELU_OUT) {
                v.x = fmaxf(v.x, 0.f); v.y = fmaxf(v.y, 0.f);
                v.z = fmaxf(v.z, 0.f); v.w = fmaxf(v.w, 0.f);
            }
            *(float4*)&C[(size_t)i * OUTW + j] = v;
        }
    }
}

// ---------- fused head tail: g1 = relu(pooled @ fc1W + fc1b); out = g1 @ fc2W + fc2b ----------
__global__ __launch_bounds__(256) void k_fc12(const float* __restrict__ A,
                                              const float* __restrict__ W,
                                              const float* __restrict__ bias,
                                              const float* __restrict__ fc2W,
                                              const float* __restrict__ fc2b,
                                              float* __restrict__ out) {
    __shared__ float At[64][68];
    __shared__ float Wt[64][128];

    int tid  = threadIdx.x;
    int colg = tid & 15;
    int rowg = tid >> 4;
    int i0 = blockIdx.x * 64;

    float acc[4][8];
#pragma unroll
    for (int r = 0; r < 4; ++r)
#pragma unroll
        for (int c = 0; c < 8; ++c) acc[r][c] = 0.0f;

    for (int k0 = 0; k0 < 256; k0 += 64) {
        __syncthreads();
        {
            int k4 = tid & 15, r0 = tid >> 4;
#pragma unroll
            for (int p = 0; p < 4; ++p) {
                int r = r0 + p * 16;
                *(float4*)&At[r][k4 * 4] =
                    *(const float4*)&A[(size_t)(i0 + r) * 256 + k0 + k4 * 4];
            }
        }
        {
            int c4 = tid & 31, kk0 = tid >> 5;
#pragma unroll
            for (int p = 0; p < 8; ++p) {
                int kk = kk0 + p * 8;
                *(float4*)&Wt[kk][c4 * 4] =
                    *(const float4*)&W[(size_t)(k0 + kk) * 128 + c4 * 4];
            }
        }
        __syncthreads();
#pragma unroll 4
        for (int kk = 0; kk < 64; ++kk) {
            float a[4];
#pragma unroll
            for (int r = 0; r < 4; ++r) a[r] = At[rowg * 4 + r][kk];
            const float4 w0 = *(const float4*)&Wt[kk][colg * 4];
            const float4 w1 = *(const float4*)&Wt[kk][64 + colg * 4];
            float w[8] = {w0.x, w0.y, w0.z, w0.w, w1.x, w1.y, w1.z, w1.w};
#pragma unroll
            for (int r = 0; r < 4; ++r)
#pragma unroll
                for (int c = 0; c < 8; ++c) acc[r][c] += a[r] * w[c];
        }
    }
    __syncthreads();
    float* g1s = &Wt[0][0];
    float* w2s = &At[0][0];
    for (int idx = tid; idx < 128 * 12; idx += 256) w2s[idx] = fc2W[idx];

#pragma unroll
    for (int r = 0; r < 4; ++r) {
        int row = rowg * 4 + r;
#pragma unroll
        for (int h = 0; h < 2; ++h) {
            int j = h * 64 + colg * 4;
            const float4 b = *(const float4*)&bias[j];
            float4 v;
            v.x = fmaxf(acc[r][h * 4 + 0] + b.x, 0.f);
            v.y = fmaxf(acc[r][h * 4 + 1] + b.y, 0.f);
            v.z = fmaxf(acc[r][h * 4 + 2] + b.z, 0.f);
            v.w = fmaxf(acc[r][h * 4 + 3] + b.w, 0.f);
            *(float4*)&g1s[row * 128 + j] = v;
        }
    }
    __syncthreads();
    for (int idx = tid; idx < 64 * 12; idx += 256) {
        int row = idx / 12, col = idx % 12;
        float o = fc2b[col];
        const float* gr = &g1s[row * 128];
        for (int k = 0; k < 128; ++k) o += gr[k] * w2s[k * 12 + col];
        out[(size_t)(i0 + row) * 12 + col] = o;
    }
}

extern "C" void kernel_launch(void* const* d_in, const int* in_sizes, int n_in,
                              void* d_out, int out_size, void* d_ws, size_t ws_size,
                              hipStream_t stream) {
    const float* x     = (const float*)d_in[0];
    const int*   ei    = (const int*)d_in[1];
    const int*   batch = (const int*)d_in[2];
    const float* W1    = (const float*)d_in[3];
    const float* b1    = (const float*)d_in[4];
    const float* W2    = (const float*)d_in[5];
    const float* b2    = (const float*)d_in[6];
    const float* W3    = (const float*)d_in[7];
    const float* b3    = (const float*)d_in[8];
    const float* fc1W  = (const float*)d_in[9];
    const float* fc1b  = (const float*)d_in[10];
    const float* fc2W  = (const float*)d_in[11];
    const float* fc2b  = (const float*)d_in[12];
    float* out = (float*)d_out;

    const int* srcp = ei;        // edge_index[0]
    const int* dstp = ei + EE;   // edge_index[1]

    // workspace layout (~45 MB)
    float* ws     = (float*)d_ws;
    __half* rh    = (__half*)ws;                   // N*128 halves = NN*64 floats
    float* Y      = ws + (size_t)NN * 64;          // G*128
    float* pooled = Y + (size_t)GG * 128;          // G*256
    float* cntf   = pooled + (size_t)GG * 256;     // G
    float* dinv   = cntf + GG;                     // N
    float* zbuf   = dinv + NN;                     // N
    float* ecoef  = zbuf + NN;                     // E
    int* indeg  = (int*)(ecoef + EE);              // N
    int* rowptr = indeg + NN;                      // N+4
    int* cursor = rowptr + NN + 4;                 // N
    int* ecol   = cursor + NN;                     // E
    int* bsum   = ecol + EE;                       // 512
    int* boff   = bsum + 512;                      // 513
    int* gstart = boff + 516;                      // G+1

    // fused front-end (cooperative): zero+count+dinv/gstart+scan+fill+z
    {
        void* args[] = {
            (void*)&srcp, (void*)&dstp, (void*)&x, (void*)&batch,
            (void*)&indeg, (void*)&bsum, (void*)&boff, (void*)&dinv,
            (void*)&gstart, (void*)&rowptr, (void*)&cursor, (void*)&ecol,
            (void*)&ecoef, (void*)&zbuf
        };
        hipLaunchCooperativeKernel((void*)k_front, dim3(512), dim3(256),
                                   args, 0, stream);
    }

    // conv2 fused: rh = fp16 relu([Â relu(z⊗W1+b1)] @ W2 + b2), dot2 MM
    k_gemm2u<<<NN / 64, 256, 0, stream>>>(zbuf, dinv, rowptr, ecol, ecoef,
                                          W1, b1, W2, b2, rh);

    // conv3 aggregation + mean pool (fp16 r)
    k_pool<<<GG, 256, 0, stream>>>(rh, dinv, rowptr, ecol, ecoef, gstart, Y, cntf);

    // head
    k_gemm<128, 256, false, true><<<dim3(GG / 64, 2), 256, 0, stream>>>(
        Y, W3, b3, cntf, pooled);
    k_fc12<<<GG / 64, 256, 0, stream>>>(pooled, fc1W, fc1b, fc2W, fc2b, out);
}

// Round 17
// 128.893 us; speedup vs baseline: 3.4993x; 3.4993x over previous
//
#include <hip/hip_runtime.h>
#include <hip/hip_fp16.h>

#define NN 131072   // nodes
#define EE 262144   // edges
#define GG 4096     // graphs

typedef _Float16 h2v __attribute__((ext_vector_type(2)));

#if __has_builtin(__builtin_amdgcn_fdot2)
#define FDOT2(a, b, c) __builtin_amdgcn_fdot2((a), (b), (c), false)
#else
#define FDOT2(a, b, c) ((float)(a)[0] * (float)(b)[0] + (float)(a)[1] * (float)(b)[1] + (c))
#endif

// ---------- custom zero ----------
__global__ void k_zero(int4* __restrict__ p, int n4) {
    int i = blockIdx.x * 256 + threadIdx.x;
    if (i < n4) p[i] = make_int4(0, 0, 0, 0);
}

// ---------- CSR build ----------
__global__ void k_count(const int* __restrict__ dst, int* __restrict__ indeg) {
    int e = blockIdx.x * 256 + threadIdx.x;
    if (e < EE) atomicAdd(&indeg[dst[e]], 1);
}

// A: per-block totals + dinv + gstart from sorted batch
__global__ __launch_bounds__(256) void k_scan_a(const int* __restrict__ indeg,
                                                int* __restrict__ bsum,
                                                float* __restrict__ dinv,
                                                const int* __restrict__ batch,
                                                int* __restrict__ gstart) {
    __shared__ int red[256];
    int tid = threadIdx.x;
    int gid = blockIdx.x * 256 + tid;
    int v = indeg[gid];
    dinv[gid] = rsqrtf((float)v + 1.0f);
    red[tid] = v;
    {
        int b1v = batch[gid];
        int b0v = (gid == 0) ? -1 : batch[gid - 1];
        for (int g = b0v + 1; g <= b1v; ++g) gstart[g] = gid;
        if (gid == NN - 1)
            for (int g = b1v + 1; g <= GG; ++g) gstart[g] = NN;
    }
    __syncthreads();
#pragma unroll
    for (int off = 128; off > 0; off >>= 1) {
        if (tid < off) red[tid] += red[tid + off];
        __syncthreads();
    }
    if (tid == 0) bsum[blockIdx.x] = red[0];
}

// C (merged with B): block offset = reduce(bsum[0..b-1]) in-block, then local scan
__global__ __launch_bounds__(256) void k_scan_c(const int* __restrict__ indeg,
                                                const int* __restrict__ bsum,
                                                int* __restrict__ rowptr,
                                                int* __restrict__ cursor) {
    __shared__ int red[256];
    __shared__ int ps[256];
    int tid = threadIdx.x;
    int b = blockIdx.x;
    int gid = b * 256 + tid;
    // block offset: sum of bsum[j] for j < b (bsum is 2KB, L2-hot; 2 loads/thread)
    int s0 = (tid < b) ? bsum[tid] : 0;
    int s1 = (tid + 256 < b) ? bsum[tid + 256] : 0;
    red[tid] = s0 + s1;
    int v = indeg[gid];
    ps[tid] = v;
    __syncthreads();
#pragma unroll
    for (int off = 128; off > 0; off >>= 1) {
        if (tid < off) red[tid] += red[tid + off];
        __syncthreads();
    }
    int boffb = red[0];
    for (int off = 1; off < 256; off <<= 1) {
        int t = (tid >= off) ? ps[tid - off] : 0;
        __syncthreads();
        ps[tid] += t;
        __syncthreads();
    }
    int excl = boffb + ps[tid] - v;
    rowptr[gid] = excl;
    cursor[gid] = excl;
    if (gid == NN - 1) rowptr[NN] = excl + v;
}

__global__ void k_fill_edges(const int* __restrict__ src, const int* __restrict__ dst,
                             const float* __restrict__ dinv,
                             int* __restrict__ cursor, int* __restrict__ ecol,
                             float* __restrict__ ecoef) {
    int e = blockIdx.x * 256 + threadIdx.x;
    if (e < EE) {
        int d = dst[e], s = src[e];
        int slot = atomicAdd(&cursor[d], 1);
        ecol[slot] = s;
        ecoef[slot] = dinv[d] * dinv[s];
    }
}

// ---------- conv1 scalar: z[i] = x_i*dinv_i^2 + sum_e ecoef[e]*x[ecol[e]] ----------
__global__ void k_z(const float* __restrict__ x, const float* __restrict__ dinv,
                    const int* __restrict__ rowptr, const int* __restrict__ ecol,
                    const float* __restrict__ ecoef, float* __restrict__ z) {
    int i = blockIdx.x * 256 + threadIdx.x;
    if (i < NN) {
        float di = dinv[i];
        float s = x[i] * di * di;
        int e0 = rowptr[i], e1 = rowptr[i + 1];
        for (int e = e0; e < e1; ++e) s += ecoef[e] * x[ecol[e]];
        z[i] = s;
    }
}

// ---------- fused conv2: rh = fp16( relu( [Â relu(z⊗W1+b1)] @ W2 + b2 ) ) ----------
// MM in packed fp16 via v_dot2_f32_f16. LDS ~25KB -> 6 blocks/CU.
__global__ __launch_bounds__(256) void k_gemm2u(const float* __restrict__ z,
                                                const float* __restrict__ dinv,
                                                const int* __restrict__ rowptr,
                                                const int* __restrict__ ecol,
                                                const float* __restrict__ ecoef,
                                                const float* __restrict__ W1,
                                                const float* __restrict__ b1,
                                                const float* __restrict__ W2,
                                                const float* __restrict__ b2,
                                                __half* __restrict__ rh) {
    __shared__ h2v At[64][33];    // [row][k-pair]
    __shared__ h2v Wt[32][128];   // [k-pair][col] — entire W2 in fp16 (16KB)
    __shared__ float w1s[64], b1s[64];

    int tid = threadIdx.x;
    int i0 = blockIdx.x * 64;

    if (tid < 64) { w1s[tid] = W1[tid]; b1s[tid] = b1[tid]; }
    {   // stage W2 as k-paired fp16
        int c4 = tid & 31, kp0 = tid >> 5;
#pragma unroll
        for (int p = 0; p < 4; ++p) {
            int kp = kp0 + p * 8;
            const float4 lo = *(const float4*)&W2[(size_t)(2 * kp) * 128 + c4 * 4];
            const float4 hi = *(const float4*)&W2[(size_t)(2 * kp + 1) * 128 + c4 * 4];
            h2v h0, h1, h2_, h3;
            h0[0] = (_Float16)lo.x; h0[1] = (_Float16)hi.x;
            h1[0] = (_Float16)lo.y; h1[1] = (_Float16)hi.y;
            h2_[0] = (_Float16)lo.z; h2_[1] = (_Float16)hi.z;
            h3[0] = (_Float16)lo.w; h3[1] = (_Float16)hi.w;
            Wt[kp][c4 * 4 + 0] = h0;
            Wt[kp][c4 * 4 + 1] = h1;
            Wt[kp][c4 * 4 + 2] = h2_;
            Wt[kp][c4 * 4 + 3] = h3;
        }
    }
    __syncthreads();

    {   // generate u rows: 4 threads per node, 16 k's each
        int n = tid >> 2;
        int kp0 = (tid & 3) * 8;
        int i = i0 + n;
        float zi = z[i], di = dinv[i];
        float d2 = di * di;
        float uacc[16];
#pragma unroll
        for (int j = 0; j < 16; ++j)
            uacc[j] = d2 * fmaxf(zi * w1s[kp0 * 2 + j] + b1s[kp0 * 2 + j], 0.f);
        int e0 = rowptr[i], e1 = rowptr[i + 1];
        for (int e = e0; e < e1; ++e) {
            float w = ecoef[e];
            float zs = z[ecol[e]];
#pragma unroll
            for (int j = 0; j < 16; ++j)
                uacc[j] += w * fmaxf(zs * w1s[kp0 * 2 + j] + b1s[kp0 * 2 + j], 0.f);
        }
#pragma unroll
        for (int j2 = 0; j2 < 8; ++j2) {
            h2v h;
            h[0] = (_Float16)uacc[2 * j2];
            h[1] = (_Float16)uacc[2 * j2 + 1];
            At[n][kp0 + j2] = h;
        }
    }
    __syncthreads();

    int colg = tid & 15;
    int rowg = tid >> 4;
    float acc[4][8];
#pragma unroll
    for (int rr = 0; rr < 4; ++rr)
#pragma unroll
        for (int c = 0; c < 8; ++c) acc[rr][c] = 0.0f;

#pragma unroll 4
    for (int kp = 0; kp < 32; ++kp) {
        h2v a2[4];
#pragma unroll
        for (int rr = 0; rr < 4; ++rr) a2[rr] = At[rowg * 4 + rr][kp];
        h2v wv[8];
        *(float4*)&wv[0] = *(const float4*)&Wt[kp][colg * 4];
        *(float4*)&wv[4] = *(const float4*)&Wt[kp][64 + colg * 4];
#pragma unroll
        for (int rr = 0; rr < 4; ++rr)
#pragma unroll
            for (int c = 0; c < 8; ++c)
                acc[rr][c] = FDOT2(a2[rr], wv[c], acc[rr][c]);
    }

#pragma unroll
    for (int rr = 0; rr < 4; ++rr) {
        int i = i0 + rowg * 4 + rr;
#pragma unroll
        for (int h = 0; h < 2; ++h) {
            int j = h * 64 + colg * 4;
            const float4 b = *(const float4*)&b2[j];
            __half2 p0 = __floats2half2_rn(fmaxf(acc[rr][h * 4 + 0] + b.x, 0.f),
                                           fmaxf(acc[rr][h * 4 + 1] + b.y, 0.f));
            __half2 p1 = __floats2half2_rn(fmaxf(acc[rr][h * 4 + 2] + b.z, 0.f),
                                           fmaxf(acc[rr][h * 4 + 3] + b.w, 0.f));
            union { __half2 h2[2]; float2 f; } u;
            u.h2[0] = p0; u.h2[1] = p1;
            *(float2*)&rh[(size_t)i * 128 + j] = u.f;
        }
    }
}

// fp16 row loader: 8 channels (16B) -> 8 floats
__device__ inline void ldr8(const __half* __restrict__ rh, size_t idx, float* o) {
    union { float4 f; __half2 h[4]; } u;
    u.f = *(const float4*)&rh[idx];
#pragma unroll
    for (int q = 0; q < 4; ++q) {
        float2 t = __half22float2(u.h[q]);
        o[q * 2] = t.x; o[q * 2 + 1] = t.y;
    }
}

// ---------- Y_g = mean_{i in g}(Â r)_i over fp16 r, 16 row-streams/block ----------
__global__ __launch_bounds__(256) void k_pool(const __half* __restrict__ rh,
                                              const float* __restrict__ dinv,
                                              const int* __restrict__ rowptr,
                                              const int* __restrict__ ecol,
                                              const float* __restrict__ ecoef,
                                              const int* __restrict__ gstart,
                                              float* __restrict__ Y,
                                              float* __restrict__ cntf) {
    int g = blockIdx.x, tid = threadIdx.x;
    int lo = gstart[g], hi = gstart[g + 1];
    int cnt = hi - lo;

    int lane = tid & 15, ty = tid >> 4;
    int c = lane * 8;
    float acc[8];
#pragma unroll
    for (int q = 0; q < 8; ++q) acc[q] = 0.f;
    float v0[8], v1[8], v2[8], v3[8];

    int i = lo + ty;
    for (; i + 16 < hi; i += 32) {
        float d0 = dinv[i], d1 = dinv[i + 16];
        ldr8(rh, (size_t)i * 128 + c, v0);
        ldr8(rh, (size_t)(i + 16) * 128 + c, v1);
        float w0 = d0 * d0, w1 = d1 * d1;
#pragma unroll
        for (int q = 0; q < 8; ++q) acc[q] += v0[q] * w0 + v1[q] * w1;
    }
    for (; i < hi; i += 16) {
        float di = dinv[i], d2 = di * di;
        ldr8(rh, (size_t)i * 128 + c, v0);
#pragma unroll
        for (int q = 0; q < 8; ++q) acc[q] += v0[q] * d2;
    }

    int e0 = rowptr[lo], e1 = rowptr[hi];
    int e = e0 + ty;
    for (; e + 48 < e1; e += 64) {
        int s0 = ecol[e], s1 = ecol[e + 16], s2 = ecol[e + 32], s3 = ecol[e + 48];
        float w0 = ecoef[e], w1 = ecoef[e + 16], w2 = ecoef[e + 32], w3 = ecoef[e + 48];
        ldr8(rh, (size_t)s0 * 128 + c, v0);
        ldr8(rh, (size_t)s1 * 128 + c, v1);
        ldr8(rh, (size_t)s2 * 128 + c, v2);
        ldr8(rh, (size_t)s3 * 128 + c, v3);
#pragma unroll
        for (int q = 0; q < 8; ++q)
            acc[q] += v0[q] * w0 + v1[q] * w1 + v2[q] * w2 + v3[q] * w3;
    }
    for (; e < e1; e += 16) {
        int s = ecol[e];
        float w = ecoef[e];
        ldr8(rh, (size_t)s * 128 + c, v0);
#pragma unroll
        for (int q = 0; q < 8; ++q) acc[q] += v0[q] * w;
    }

    __shared__ float red[16][128];
    *(float4*)&red[ty][c]     = make_float4(acc[0], acc[1], acc[2], acc[3]);
    *(float4*)&red[ty][c + 4] = make_float4(acc[4], acc[5], acc[6], acc[7]);
    __syncthreads();
    if (tid < 128) {
        float s = 0.0f;
#pragma unroll
        for (int t = 0; t < 16; ++t) s += red[t][tid];
        float inv = (cnt > 0) ? 1.0f / (float)cnt : 0.0f;
        Y[(size_t)g * 128 + tid] = s * inv;
    }
    if (tid == 0) cntf[g] = (float)cnt;
}

// ---------- generic register-tiled GEMM: C = [relu](A @ W + bias[*flag]) ----------
template <int K, int OUTW, bool RELU_OUT, bool GUARD>
__global__ __launch_bounds__(256) void k_gemm(const float* __restrict__ A,
                                              const float* __restrict__ W,
                                              const float* __restrict__ bias,
                                              const float* __restrict__ cntf,
                                              float* __restrict__ C) {
    __shared__ float At[64][68];
    __shared__ float Wt[64][128];

    int tid  = threadIdx.x;
    int colg = tid & 15;
    int rowg = tid >> 4;
    int i0 = blockIdx.x * 64;
    int j0 = blockIdx.y * 128;

    float acc[4][8];
#pragma unroll
    for (int r = 0; r < 4; ++r)
#pragma unroll
        for (int c = 0; c < 8; ++c) acc[r][c] = 0.0f;

    for (int k0 = 0; k0 < K; k0 += 64) {
        __syncthreads();
        {
            int k4 = tid & 15, r0 = tid >> 4;
#pragma unroll
            for (int p = 0; p < 4; ++p) {
                int r = r0 + p * 16;
                *(float4*)&At[r][k4 * 4] =
                    *(const float4*)&A[(size_t)(i0 + r) * K + k0 + k4 * 4];
            }
        }
        {
            int c4 = tid & 31, kk0 = tid >> 5;
#pragma unroll
            for (int p = 0; p < 8; ++p) {
                int kk = kk0 + p * 8;
                *(float4*)&Wt[kk][c4 * 4] =
                    *(const float4*)&W[(size_t)(k0 + kk) * OUTW + j0 + c4 * 4];
            }
        }
        __syncthreads();
#pragma unroll 4
        for (int kk = 0; kk < 64; ++kk) {
            float a[4];
#pragma unroll
            for (int r = 0; r < 4; ++r) a[r] = At[rowg * 4 + r][kk];
            const float4 w0 = *(const float4*)&Wt[kk][colg * 4];
            const float4 w1 = *(const float4*)&Wt[kk][64 + colg * 4];
            float w[8] = {w0.x, w0.y, w0.z, w0.w, w1.x, w1.y, w1.z, w1.w};
#pragma unroll
            for (int r = 0; r < 4; ++r)
#pragma unroll
                for (int c = 0; c < 8; ++c) acc[r][c] += a[r] * w[c];
        }
    }

#pragma unroll
    for (int r = 0; r < 4; ++r) {
        int i = i0 + rowg * 4 + r;
        float flag = 1.0f;
        if (GUARD) flag = (cntf[i] > 0.0f) ? 1.0f : 0.0f;
#pragma unroll
        for (int h = 0; h < 2; ++h) {
            int j = j0 + h * 64 + colg * 4;
            const float4 b = *(const float4*)&bias[j];
            float4 v;
            v.x = acc[r][h * 4 + 0] + b.x * flag;
            v.y = acc[r][h * 4 + 1] + b.y * flag;
            v.z = acc[r][h * 4 + 2] + b.z * flag;
            v.w = acc[r][h * 4 + 3] + b.w * flag;
            if (RELU_OUT) {
                v.x = fmaxf(v.x, 0.f); v.y = fmaxf(v.y, 0.f);
                v.z = fmaxf(v.z, 0.f); v.w = fmaxf(v.w, 0.f);
            }
            *(float4*)&C[(size_t)i * OUTW + j] = v;
        }
    }
}

// ---------- fused head tail: g1 = relu(pooled @ fc1W + fc1b); out = g1 @ fc2W + fc2b ----------
__global__ __launch_bounds__(256) void k_fc12(const float* __restrict__ A,
                                              const float* __restrict__ W,
                                              const float* __restrict__ bias,
                                              const float* __restrict__ fc2W,
                                              const float* __restrict__ fc2b,
                                              float* __restrict__ out) {
    __shared__ float At[64][68];
    __shared__ float Wt[64][128];

    int tid  = threadIdx.x;
    int colg = tid & 15;
    int rowg = tid >> 4;
    int i0 = blockIdx.x * 64;

    float acc[4][8];
#pragma unroll
    for (int r = 0; r < 4; ++r)
#pragma unroll
        for (int c = 0; c < 8; ++c) acc[r][c] = 0.0f;

    for (int k0 = 0; k0 < 256; k0 += 64) {
        __syncthreads();
        {
            int k4 = tid & 15, r0 = tid >> 4;
#pragma unroll
            for (int p = 0; p < 4; ++p) {
                int r = r0 + p * 16;
                *(float4*)&At[r][k4 * 4] =
                    *(const float4*)&A[(size_t)(i0 + r) * 256 + k0 + k4 * 4];
            }
        }
        {
            int c4 = tid & 31, kk0 = tid >> 5;
#pragma unroll
            for (int p = 0; p < 8; ++p) {
                int kk = kk0 + p * 8;
                *(float4*)&Wt[kk][c4 * 4] =
                    *(const float4*)&W[(size_t)(k0 + kk) * 128 + c4 * 4];
            }
        }
        __syncthreads();
#pragma unroll 4
        for (int kk = 0; kk < 64; ++kk) {
            float a[4];
#pragma unroll
            for (int r = 0; r < 4; ++r) a[r] = At[rowg * 4 + r][kk];
            const float4 w0 = *(const float4*)&Wt[kk][colg * 4];
            const float4 w1 = *(const float4*)&Wt[kk][64 + colg * 4];
            float w[8] = {w0.x, w0.y, w0.z, w0.w, w1.x, w1.y, w1.z, w1.w};
#pragma unroll
            for (int r = 0; r < 4; ++r)
#pragma unroll
                for (int c = 0; c < 8; ++c) acc[r][c] += a[r] * w[c];
        }
    }
    __syncthreads();
    float* g1s = &Wt[0][0];
    float* w2s = &At[0][0];
    for (int idx = tid; idx < 128 * 12; idx += 256) w2s[idx] = fc2W[idx];

#pragma unroll
    for (int r = 0; r < 4; ++r) {
        int row = rowg * 4 + r;
#pragma unroll
        for (int h = 0; h < 2; ++h) {
            int j = h * 64 + colg * 4;
            const float4 b = *(const float4*)&bias[j];
            float4 v;
            v.x = fmaxf(acc[r][h * 4 + 0] + b.x, 0.f);
            v.y = fmaxf(acc[r][h * 4 + 1] + b.y, 0.f);
            v.z = fmaxf(acc[r][h * 4 + 2] + b.z, 0.f);
            v.w = fmaxf(acc[r][h * 4 + 3] + b.w, 0.f);
            *(float4*)&g1s[row * 128 + j] = v;
        }
    }
    __syncthreads();
    for (int idx = tid; idx < 64 * 12; idx += 256) {
        int row = idx / 12, col = idx % 12;
        float o = fc2b[col];
        const float* gr = &g1s[row * 128];
        for (int k = 0; k < 128; ++k) o += gr[k] * w2s[k * 12 + col];
        out[(size_t)(i0 + row) * 12 + col] = o;
    }
}

extern "C" void kernel_launch(void* const* d_in, const int* in_sizes, int n_in,
                              void* d_out, int out_size, void* d_ws, size_t ws_size,
                              hipStream_t stream) {
    const float* x     = (const float*)d_in[0];
    const int*   ei    = (const int*)d_in[1];
    const int*   batch = (const int*)d_in[2];
    const float* W1    = (const float*)d_in[3];
    const float* b1    = (const float*)d_in[4];
    const float* W2    = (const float*)d_in[5];
    const float* b2    = (const float*)d_in[6];
    const float* W3    = (const float*)d_in[7];
    const float* b3    = (const float*)d_in[8];
    const float* fc1W  = (const float*)d_in[9];
    const float* fc1b  = (const float*)d_in[10];
    const float* fc2W  = (const float*)d_in[11];
    const float* fc2b  = (const float*)d_in[12];
    float* out = (float*)d_out;

    const int* srcp = ei;        // edge_index[0]
    const int* dstp = ei + EE;   // edge_index[1]

    // workspace layout (~45 MB)
    float* ws     = (float*)d_ws;
    __half* rh    = (__half*)ws;                   // N*128 halves = NN*64 floats
    float* Y      = ws + (size_t)NN * 64;          // G*128
    float* pooled = Y + (size_t)GG * 128;          // G*256
    float* cntf   = pooled + (size_t)GG * 256;     // G
    float* dinv   = cntf + GG;                     // N
    float* zbuf   = dinv + NN;                     // N
    float* ecoef  = zbuf + NN;                     // E
    int* indeg  = (int*)(ecoef + EE);              // N
    int* rowptr = indeg + NN;                      // N+4
    int* cursor = rowptr + NN + 4;                 // N
    int* ecol   = cursor + NN;                     // E
    int* bsum   = ecol + EE;                       // 512
    int* gstart = bsum + 512;                      // G+1

    // CSR build (scan_b merged into scan_c)
    k_zero<<<NN / 4 / 256, 256, 0, stream>>>((int4*)indeg, NN / 4);
    k_count<<<EE / 256, 256, 0, stream>>>(dstp, indeg);
    k_scan_a<<<NN / 256, 256, 0, stream>>>(indeg, bsum, dinv, batch, gstart);
    k_scan_c<<<NN / 256, 256, 0, stream>>>(indeg, bsum, rowptr, cursor);
    k_fill_edges<<<EE / 256, 256, 0, stream>>>(srcp, dstp, dinv, cursor, ecol, ecoef);

    // conv1 scalar
    k_z<<<NN / 256, 256, 0, stream>>>(x, dinv, rowptr, ecol, ecoef, zbuf);

    // conv2 fused: rh = fp16 relu([Â relu(z⊗W1+b1)] @ W2 + b2), dot2 MM
    k_gemm2u<<<NN / 64, 256, 0, stream>>>(zbuf, dinv, rowptr, ecol, ecoef,
                                          W1, b1, W2, b2, rh);

    // conv3 aggregation + mean pool (fp16 r)
    k_pool<<<GG, 256, 0, stream>>>(rh, dinv, rowptr, ecol, ecoef, gstart, Y, cntf);

    // head
    k_gemm<128, 256, false, true><<<dim3(GG / 64, 2), 256, 0, stream>>>(
        Y, W3, b3, cntf, pooled);
    k_fc12<<<GG / 64, 256, 0, stream>>>(pooled, fc1W, fc1b, fc2W, fc2b, out);
}